// Round 4
// baseline (463.378 us; speedup 1.0000x reference)
//
#include <hip/hip_runtime.h>
#include <hip/hip_bf16.h>

#define NN 10000
#define INC 32
#define OUTC 32
#define EF 16
#define NE 320000
#define NTILES (NE / 32)   // 10000 tiles of 32 edges

typedef __attribute__((ext_vector_type(8)))  __bf16 bf16x8;
typedef __attribute__((ext_vector_type(16))) float  f32x16;
typedef __attribute__((ext_vector_type(4)))  float  f32x4;

// ======================= zero (cnt + summed) =======================
__global__ void zero_kernel(int* __restrict__ cnt, float* __restrict__ summed) {
    int gid = blockIdx.x * 256 + threadIdx.x;
    if (gid < NN) cnt[gid] = 0;
    if (gid < NN * 32) summed[gid] = 0.0f;
}

// ======================= CSR build =======================
__global__ void hist_kernel(const int* __restrict__ eidx, int* __restrict__ cnt) {
    for (int e = blockIdx.x * 256 + threadIdx.x; e < NE; e += gridDim.x * 256)
        atomicAdd(&cnt[eidx[NE + e]], 1);
}

// single block, 1024 threads: exclusive scan of cnt[0..NN) -> offs, copy to pos
__global__ __launch_bounds__(1024) void scan_kernel(const int* __restrict__ cnt,
                                                    int* __restrict__ offs,
                                                    int* __restrict__ pos) {
    __shared__ int s[1024];
    const int t = threadIdx.x;
    const int base = t * 10;
    int loc[10];
    int sum = 0;
    #pragma unroll
    for (int k = 0; k < 10; ++k) {
        int idx = base + k;
        int v = (idx < NN) ? cnt[idx] : 0;
        loc[k] = sum;
        sum += v;
    }
    s[t] = sum;
    __syncthreads();
    for (int off = 1; off < 1024; off <<= 1) {
        int v = 0;
        if (t >= off) v = s[t - off];
        __syncthreads();
        if (t >= off) s[t] += v;
        __syncthreads();
    }
    int excl = (t > 0) ? s[t - 1] : 0;
    #pragma unroll
    for (int k = 0; k < 10; ++k) {
        int idx = base + k;
        if (idx < NN) {
            int o = excl + loc[k];
            offs[idx] = o;
            pos[idx]  = o;
        }
    }
    if (t == 1023) offs[NN] = s[1023];
}

__global__ void scatter_kernel(const int* __restrict__ eidx, int* __restrict__ pos,
                               int* __restrict__ perm, int* __restrict__ dsts) {
    for (int e = blockIdx.x * 256 + threadIdx.x; e < NE; e += gridDim.x * 256) {
        int d = eidx[NE + e];
        int p = atomicAdd(&pos[d], 1);
        perm[p] = e;
        dsts[p] = d;
    }
}

// ======================= fused edge + aggregate kernel =======================
// Per wave: tile of 32 dst-sorted slots. MFMA 32x32x16 bf16:
//   A[m][k] = W_edge[k][cb*32+m], B[k][n] = edge_attr[e(n)][k], C = b_edge bias (f32x16 from LDS)
//   D layout: col = lane&31 = slot ; row r -> channel o = (r&3)+8*(r>>2)+4*(lane>>5)
// msg accumulated lane-locally over cb (i = cb), then segmented-sum across the 32
// slot-lanes (dst non-decreasing), segment tails flush via f32 atomics.
__global__ __launch_bounds__(256, 3) void edge_fused_kernel(
    const float* __restrict__ x, const int* __restrict__ eidx,
    const float* __restrict__ ea, const float* __restrict__ W,
    const float* __restrict__ be, const int* __restrict__ perm,
    const int* __restrict__ dsts, float* __restrict__ summed)
{
    __shared__ __attribute__((aligned(16))) __bf16 WT[32][2][32][8];  // 32 KiB
    __shared__ __attribute__((aligned(16))) float  BPF[32][2][16];    // 4 KiB permuted f32 bias

    const int tid = threadIdx.x;

    #pragma unroll
    for (int k = 0; k < 8; ++k) {
        int idx = tid + k * 256;              // (cb, hi, c)
        int cb = idx >> 6, rem = idx & 63, hi2 = rem >> 5, c = rem & 31;
        int cg = cb * 32 + c;
        #pragma unroll
        for (int j = 0; j < 8; ++j)
            WT[cb][hi2][c][j] = (__bf16)W[(8 * hi2 + j) * 1024 + cg];
    }
    #pragma unroll
    for (int k = 0; k < 4; ++k) {
        int idx = tid + k * 256;              // (cb, hi, r)
        int cb = idx >> 5, rem = idx & 31, hi2 = rem >> 4, r = rem & 15;
        int row = (r & 3) + 8 * (r >> 2) + 4 * hi2;
        BPF[cb][hi2][r] = be[cb * 32 + row];
    }
    __syncthreads();

    const int lane = tid & 63;
    const int hi   = lane >> 5;
    const int l31  = lane & 31;
    const int hbit = lane & 32;               // for same-half shfl source
    const int wid  = blockIdx.x * 4 + (tid >> 6);
    const int nw   = gridDim.x * 4;

    for (int tile = wid; tile < NTILES; tile += nw) {
        const int j = tile * 32 + l31;        // sorted slot
        const int e = __builtin_nontemporal_load(perm + j);
        const int d = __builtin_nontemporal_load(dsts + j);
        const int src = eidx[e];

        const f32x4* eap = (const f32x4*)(ea + e * 16 + hi * 8);
        f32x4 f0 = __builtin_nontemporal_load(eap);
        f32x4 f1 = __builtin_nontemporal_load(eap + 1);
        bf16x8 bfrag;
        bfrag[0] = (__bf16)f0.x; bfrag[1] = (__bf16)f0.y;
        bfrag[2] = (__bf16)f0.z; bfrag[3] = (__bf16)f0.w;
        bfrag[4] = (__bf16)f1.x; bfrag[5] = (__bf16)f1.y;
        bfrag[6] = (__bf16)f1.z; bfrag[7] = (__bf16)f1.w;

        const float4* xp = (const float4*)(x + src * 32);

        float msgr[16];
        #pragma unroll
        for (int r = 0; r < 16; ++r) msgr[r] = 0.0f;

        #pragma unroll
        for (int cbq = 0; cbq < 8; ++cbq) {
            float4 xq = xp[cbq];
            #pragma unroll
            for (int c4 = 0; c4 < 4; ++c4) {
                const int cb = cbq * 4 + c4;
                bf16x8 af = *(const bf16x8*)(&WT[cb][hi][l31][0]);
                const f32x16* bp = (const f32x16*)(&BPF[cb][hi][0]);
                f32x16 acc = __builtin_amdgcn_mfma_f32_32x32x16_bf16(af, bfrag, *bp, 0, 0, 0);
                const float xv = (c4 == 0) ? xq.x : (c4 == 1) ? xq.y : (c4 == 2) ? xq.z : xq.w;
                #pragma unroll
                for (int r = 0; r < 16; ++r)
                    msgr[r] += fmaxf(acc[r], 0.0f) * xv;
            }
        }

        // ---- segmented inclusive scan across the 32 slot-lanes (keys sorted) ----
        #pragma unroll
        for (int s = 1; s < 32; s <<= 1) {
            const int srcl = hbit | ((l31 - s) & 31);
            const int dp   = __shfl(d, srcl, 64);
            const bool same = (l31 >= s) && (dp == d);
            #pragma unroll
            for (int r = 0; r < 16; ++r) {
                const float t = __shfl(msgr[r], srcl, 64);
                msgr[r] += same ? t : 0.0f;
            }
        }
        // segment tail?
        const int dnx = __shfl(d, hbit | ((l31 + 1) & 31), 64);
        const bool last = (l31 == 31) || (dnx != d);
        if (last) {
            float* sb = summed + (size_t)d * 32;
            #pragma unroll
            for (int r = 0; r < 16; ++r) {
                const int o = (r & 3) + 8 * (r >> 2) + 4 * hi;
                unsafeAtomicAdd(sb + o, msgr[r]);
            }
        }
    }
}

// ======================= finalize =======================
__global__ __launch_bounds__(256) void finalize_kernel(
    const float* __restrict__ x, const float* __restrict__ root,
    const float* __restrict__ bias, const int* __restrict__ offs,
    const float* __restrict__ summed, float* __restrict__ out)
{
    int gid = blockIdx.x * 256 + threadIdx.x;
    if (gid >= NN * 32) return;
    int n = gid >> 5, o = gid & 31;
    float deg = (float)(offs[n + 1] - offs[n]);
    float acc = summed[gid] / fmaxf(deg, 1.0f) + bias[o];
    const float* xr = x + n * 32;
    #pragma unroll
    for (int i = 0; i < 32; ++i)
        acc += xr[i] * root[i * 32 + o];
    out[gid] = acc;
}

// ======================= launch =======================
extern "C" void kernel_launch(void* const* d_in, const int* in_sizes, int n_in,
                              void* d_out, int out_size, void* d_ws, size_t ws_size,
                              hipStream_t stream) {
    const float* x    = (const float*)d_in[0];
    const int*   eidx = (const int*)d_in[1];     // [2][NE]
    const float* ea   = (const float*)d_in[2];   // [NE][16]
    const float* W    = (const float*)d_in[3];   // [16][1024]
    const float* be   = (const float*)d_in[4];   // [1024]
    const float* root = (const float*)d_in[5];   // [32][32]
    const float* bias = (const float*)d_in[6];   // [32]
    float* out = (float*)d_out;

    // ws (ints/f32): cnt[NN] | offs[NN+1] | pos[NN] | perm[NE] | dsts[NE] | summed[NN*32]
    int* cnt  = (int*)d_ws;
    int* offs = cnt + NN;
    int* pos  = offs + NN + 1;
    int* perm = pos + NN;
    int* dsts = perm + NE;
    float* summed = (float*)(dsts + NE) + 3;     // keep 16B alignment headroom

    zero_kernel<<<(NN * 32 + 255) / 256, 256, 0, stream>>>(cnt, summed);
    hist_kernel<<<640, 256, 0, stream>>>(eidx, cnt);
    scan_kernel<<<1, 1024, 0, stream>>>(cnt, offs, pos);
    scatter_kernel<<<640, 256, 0, stream>>>(eidx, pos, perm, dsts);
    edge_fused_kernel<<<640, 256, 0, stream>>>(x, eidx, ea, W, be, perm, dsts, summed);
    finalize_kernel<<<(NN * 32 + 255) / 256, 256, 0, stream>>>(x, root, bias, offs, summed, out);
}

// Round 5
// 411.015 us; speedup vs baseline: 1.1274x; 1.1274x over previous
//
#include <hip/hip_runtime.h>
#include <hip/hip_bf16.h>

#define NN 10000
#define INC 32
#define OUTC 32
#define EF 16
#define NE 320000

typedef __attribute__((ext_vector_type(8)))  __bf16 bf16x8;
typedef __attribute__((ext_vector_type(16))) float  f32x16;
typedef __attribute__((ext_vector_type(4)))  float  f32x4;

// ======================= zero cnt =======================
__global__ void zero_kernel(int* __restrict__ cnt) {
    int gid = blockIdx.x * 256 + threadIdx.x;
    if (gid < NN) cnt[gid] = 0;
}

// ======================= CSR build =======================
__global__ void hist_kernel(const int* __restrict__ eidx, int* __restrict__ cnt) {
    for (int e = blockIdx.x * 256 + threadIdx.x; e < NE; e += gridDim.x * 256)
        atomicAdd(&cnt[eidx[NE + e]], 1);
}

// single block, 1024 threads: exclusive scan of cnt[0..NN) -> offs, copy to pos
__global__ __launch_bounds__(1024) void scan_kernel(const int* __restrict__ cnt,
                                                    int* __restrict__ offs,
                                                    int* __restrict__ pos) {
    __shared__ int s[1024];
    const int t = threadIdx.x;
    const int base = t * 10;
    int loc[10];
    int sum = 0;
    #pragma unroll
    for (int k = 0; k < 10; ++k) {
        int idx = base + k;
        int v = (idx < NN) ? cnt[idx] : 0;
        loc[k] = sum;
        sum += v;
    }
    s[t] = sum;
    __syncthreads();
    for (int off = 1; off < 1024; off <<= 1) {
        int v = 0;
        if (t >= off) v = s[t - off];
        __syncthreads();
        if (t >= off) s[t] += v;
        __syncthreads();
    }
    int excl = (t > 0) ? s[t - 1] : 0;
    #pragma unroll
    for (int k = 0; k < 10; ++k) {
        int idx = base + k;
        if (idx < NN) {
            int o = excl + loc[k];
            offs[idx] = o;
            pos[idx]  = o;
        }
    }
    if (t == 1023) offs[NN] = s[1023];
}

// also emits srcs[] so the edge kernel reads src sequentially (no eidx gather)
__global__ void scatter_kernel(const int* __restrict__ eidx, int* __restrict__ pos,
                               int* __restrict__ perm, int* __restrict__ srcs) {
    for (int e = blockIdx.x * 256 + threadIdx.x; e < NE; e += gridDim.x * 256) {
        int d = eidx[NE + e];
        int s = eidx[e];
        int p = atomicAdd(&pos[d], 1);
        perm[p] = e;
        srcs[p] = s;
    }
}

// ======================= node-centric fused edge kernel =======================
// One wave per dst node n (grid = NN/4 blocks x 4 waves, exact). Walk the CSR
// segment [offs[n], offs[n+1]) in 32-edge chunks through MFMA 32x32x16 bf16:
//   A[m][k] = W_edge[k][cb*32+m] (LDS), B[k][slot] = edge_attr[e(slot)][k],
//   C = permuted f32 bias. D: col = lane&31 = slot; row r -> channel
//   o = (r&3)+8*(r>>2)+4*(lane>>5).  msgr accumulates over (cb, chunks) in
//   registers; ONE xor-butterfly over the 32 slot-lanes at the end; two lanes
//   store 4 x float4 each. No atomics, 1.28 MB total writes.
__global__ __launch_bounds__(256) void edge_node_kernel(
    const float* __restrict__ x, const float* __restrict__ ea,
    const float* __restrict__ W, const float* __restrict__ be,
    const int* __restrict__ offs, const int* __restrict__ perm,
    const int* __restrict__ srcs, float* __restrict__ out)
{
    __shared__ __attribute__((aligned(16))) __bf16 WT[32][2][32][8];  // 32 KiB
    __shared__ __attribute__((aligned(16))) float  BPF[32][2][16];    // 4 KiB

    const int tid = threadIdx.x;

    #pragma unroll
    for (int k = 0; k < 8; ++k) {
        int idx = tid + k * 256;              // (cb, hi, c)
        int cb = idx >> 6, rem = idx & 63, hi2 = rem >> 5, c = rem & 31;
        int cg = cb * 32 + c;
        #pragma unroll
        for (int j = 0; j < 8; ++j)
            WT[cb][hi2][c][j] = (__bf16)W[(8 * hi2 + j) * 1024 + cg];
    }
    #pragma unroll
    for (int k = 0; k < 4; ++k) {
        int idx = tid + k * 256;              // (cb, hi, r)
        int cb = idx >> 5, rem = idx & 31, hi2 = rem >> 4, r = rem & 15;
        int row = (r & 3) + 8 * (r >> 2) + 4 * hi2;
        BPF[cb][hi2][r] = be[cb * 32 + row];
    }
    __syncthreads();

    const int lane = tid & 63;
    const int hi   = lane >> 5;
    const int l31  = lane & 31;
    const int n    = blockIdx.x * 4 + (tid >> 6);   // exact: gridDim.x = NN/4

    const int a   = offs[n];
    const int b   = offs[n + 1];
    const int deg = b - a;

    float msgr[16];
    #pragma unroll
    for (int r = 0; r < 16; ++r) msgr[r] = 0.0f;

    for (int c0 = 0; c0 < deg; c0 += 32) {
        const int idx  = c0 + l31;
        const bool act = idx < deg;
        const int j    = a + (act ? idx : deg - 1);   // clamp inside segment
        const int e    = __builtin_nontemporal_load(perm + j);
        const int src  = __builtin_nontemporal_load(srcs + j);

        const f32x4* eap = (const f32x4*)(ea + e * 16 + hi * 8);
        f32x4 f0 = __builtin_nontemporal_load(eap);
        f32x4 f1 = __builtin_nontemporal_load(eap + 1);
        bf16x8 bfrag;
        bfrag[0] = (__bf16)f0.x; bfrag[1] = (__bf16)f0.y;
        bfrag[2] = (__bf16)f0.z; bfrag[3] = (__bf16)f0.w;
        bfrag[4] = (__bf16)f1.x; bfrag[5] = (__bf16)f1.y;
        bfrag[6] = (__bf16)f1.z; bfrag[7] = (__bf16)f1.w;

        const float4* xp = (const float4*)(x + src * 32);

        #pragma unroll
        for (int cbq = 0; cbq < 8; ++cbq) {
            float4 xq = xp[cbq];
            if (!act) { xq.x = 0.0f; xq.y = 0.0f; xq.z = 0.0f; xq.w = 0.0f; }
            #pragma unroll
            for (int c4 = 0; c4 < 4; ++c4) {
                const int cb = cbq * 4 + c4;
                bf16x8 af = *(const bf16x8*)(&WT[cb][hi][l31][0]);
                const f32x16* bp = (const f32x16*)(&BPF[cb][hi][0]);
                f32x16 acc = __builtin_amdgcn_mfma_f32_32x32x16_bf16(af, bfrag, *bp, 0, 0, 0);
                const float xv = (c4 == 0) ? xq.x : (c4 == 1) ? xq.y : (c4 == 2) ? xq.z : xq.w;
                #pragma unroll
                for (int r = 0; r < 16; ++r)
                    msgr[r] += fmaxf(acc[r], 0.0f) * xv;
            }
        }
    }

    // reduce across the 32 slot-lanes within each hi-half (masks < 32 never cross)
    #pragma unroll
    for (int m = 1; m <= 16; m <<= 1) {
        #pragma unroll
        for (int r = 0; r < 16; ++r)
            msgr[r] += __shfl_xor(msgr[r], m, 64);
    }

    const float rdeg = (deg > 0) ? (1.0f / (float)deg) : 0.0f;
    if (l31 == 0) {
        float4* orow = (float4*)(out + (size_t)n * 32);
        #pragma unroll
        for (int q = 0; q < 4; ++q)
            orow[2 * q + hi] = make_float4(msgr[4*q] * rdeg, msgr[4*q+1] * rdeg,
                                           msgr[4*q+2] * rdeg, msgr[4*q+3] * rdeg);
    }
}

// ======================= finalize: out += x@root + bias =======================
__global__ __launch_bounds__(256) void finalize_kernel(
    const float* __restrict__ x, const float* __restrict__ root,
    const float* __restrict__ bias, float* __restrict__ out)
{
    int gid = blockIdx.x * 256 + threadIdx.x;
    if (gid >= NN * 32) return;
    int n = gid >> 5, o = gid & 31;
    float acc = out[gid] + bias[o];
    const float* xr = x + n * 32;
    #pragma unroll
    for (int i = 0; i < 32; ++i)
        acc += xr[i] * root[i * 32 + o];
    out[gid] = acc;
}

// ======================= launch =======================
extern "C" void kernel_launch(void* const* d_in, const int* in_sizes, int n_in,
                              void* d_out, int out_size, void* d_ws, size_t ws_size,
                              hipStream_t stream) {
    const float* x    = (const float*)d_in[0];
    const int*   eidx = (const int*)d_in[1];     // [2][NE]
    const float* ea   = (const float*)d_in[2];   // [NE][16]
    const float* W    = (const float*)d_in[3];   // [16][1024]
    const float* be   = (const float*)d_in[4];   // [1024]
    const float* root = (const float*)d_in[5];   // [32][32]
    const float* bias = (const float*)d_in[6];   // [32]
    float* out = (float*)d_out;

    // ws (ints): cnt[NN] | offs[NN+1] | pos[NN] | perm[NE] | srcs[NE]
    int* cnt  = (int*)d_ws;
    int* offs = cnt + NN;
    int* pos  = offs + NN + 1;
    int* perm = pos + NN;
    int* srcs = perm + NE;

    zero_kernel<<<(NN + 255) / 256, 256, 0, stream>>>(cnt);
    hist_kernel<<<640, 256, 0, stream>>>(eidx, cnt);
    scan_kernel<<<1, 1024, 0, stream>>>(cnt, offs, pos);
    scatter_kernel<<<640, 256, 0, stream>>>(eidx, pos, perm, srcs);
    edge_node_kernel<<<NN / 4, 256, 0, stream>>>(x, ea, W, be, offs, perm, srcs, out);
    finalize_kernel<<<(NN * 32 + 255) / 256, 256, 0, stream>>>(x, root, bias, out);
}